// Round 11
// baseline (142.918 us; speedup 1.0000x reference)
//
#include <hip/hip_runtime.h>

#define DDIM 128
#define MSUB 8
#define KCODE 256
#define DSUB 16
#define NLIST 1024
#define NPROBE 32
#define TOPK 100
#define HBINS 4096
#define COLL_CAP 2048
#define RCAP 10
#define SCHUNK 512
#define STHREADS 512
#define PSTRIDE 66   // per-query probe descriptor: 32 pstart + 33 pcum

// ==== FROZEN ARITHMETIC (bit-exact vs reference — do not modify) ====

__device__ __forceinline__ float xla_sumsq128(const float* x) {
  float s[16];
  #pragma unroll
  for (int j = 0; j < 16; ++j) {
    float p0 = __fmul_rn(x[j],       x[j]);
    float p1 = __fmul_rn(x[j + 16],  x[j + 16]);
    float p2 = __fmul_rn(x[j + 32],  x[j + 32]);
    float p3 = __fmul_rn(x[j + 48],  x[j + 48]);
    float p4 = __fmul_rn(x[j + 64],  x[j + 64]);
    float p5 = __fmul_rn(x[j + 80],  x[j + 80]);
    float p6 = __fmul_rn(x[j + 96],  x[j + 96]);
    float p7 = __fmul_rn(x[j + 112], x[j + 112]);
    float r0 = __fadd_rn(p0, p4);
    float r1 = __fadd_rn(p1, p5);
    float r2 = __fadd_rn(p2, p6);
    float r3 = __fadd_rn(p3, p7);
    s[j] = __fadd_rn(__fadd_rn(r0, r1), __fadd_rn(r2, r3));
  }
  float a[8], b[4], c[2];
  #pragma unroll
  for (int j = 0; j < 8; ++j) a[j] = __fadd_rn(s[j], s[j + 8]);
  #pragma unroll
  for (int j = 0; j < 4; ++j) b[j] = __fadd_rn(a[j], a[j + 4]);
  #pragma unroll
  for (int j = 0; j < 2; ++j) c[j] = __fadd_rn(b[j], b[j + 2]);
  return __fadd_rn(c[0], c[1]);
}

__device__ __forceinline__ float xla_sumsq16(const float* x) {
  float p[16];
  #pragma unroll
  for (int j = 0; j < 16; ++j) p[j] = __fmul_rn(x[j], x[j]);
  float s8[8], s4[4], s2[2];
  #pragma unroll
  for (int j = 0; j < 8; ++j) s8[j] = __fadd_rn(p[j], p[j + 8]);
  #pragma unroll
  for (int j = 0; j < 4; ++j) s4[j] = __fadd_rn(s8[j], s8[j + 4]);
  #pragma unroll
  for (int j = 0; j < 2; ++j) s2[j] = __fadd_rn(s4[j], s4[j + 2]);
  return __fadd_rn(s2[0], s2[1]);
}

__device__ __forceinline__ float chain_dot16(const float* a, const float* b) {
  float dot = 0.f;
  #pragma unroll
  for (int d = 0; d < DSUB; ++d) dot = __fmaf_rn(a[d], b[d], dot);
  return dot;
}

__device__ __forceinline__ float adc_dist(const float* lut, unsigned long long code) {
  float d = lut[(unsigned)(code & 255ULL)];
  d = __fadd_rn(d, lut[256  + (unsigned)((code >> 8)  & 255ULL)]);
  d = __fadd_rn(d, lut[512  + (unsigned)((code >> 16) & 255ULL)]);
  d = __fadd_rn(d, lut[768  + (unsigned)((code >> 24) & 255ULL)]);
  d = __fadd_rn(d, lut[1024 + (unsigned)((code >> 32) & 255ULL)]);
  d = __fadd_rn(d, lut[1280 + (unsigned)((code >> 40) & 255ULL)]);
  d = __fadd_rn(d, lut[1536 + (unsigned)((code >> 48) & 255ULL)]);
  d = __fadd_rn(d, lut[1792 + (unsigned)((code >> 56) & 255ULL)]);
  return d;
}

// ==== helpers ====
__device__ __forceinline__ unsigned block_scan_incl(unsigned v, volatile unsigned* wsum,
                                                    int t, int nwaves) {
  int lane = t & 63, wid = t >> 6;
  #pragma unroll
  for (int off = 1; off < 64; off <<= 1) {
    unsigned u = __shfl_up(v, off, 64);
    if (lane >= off) v += u;
  }
  if (lane == 63) wsum[wid] = v;
  __syncthreads();
  if (wid == 0 && lane < nwaves) {
    unsigned wv = wsum[lane];
    #pragma unroll
    for (int off = 1; off < 16; off <<= 1) {
      unsigned u = __shfl_up(wv, off, 64);
      if (lane >= off) wv += u;
    }
    wsum[lane] = wv;
  }
  __syncthreads();
  return v + (wid > 0 ? wsum[wid - 1] : 0u);
}

// ------- front: 4-query coarse roles (256) + LDS-aggregated db_list hist roles
//         (256, exact R8 body), interleaved bid&1 over a 512-block grid.
//         Coarse: each block serves queries 4*qg..4*qg+3 with ONE centroid fetch
//         + ONE cc=sumsq(centroid) per thread (bit-exact reuse) -> quarters
//         centroid L2 traffic vs 1 query/block.
__global__ __launch_bounds__(256) void k_front(const float* __restrict__ queries,
                                               const float* __restrict__ centroids,
                                               const int* __restrict__ db_list, int N,
                                               unsigned long long* __restrict__ keys_g,
                                               unsigned* __restrict__ counts) {
  const int t = threadIdx.x;
  const int r  = blockIdx.x & 1;
  const int b2 = blockIdx.x >> 1;

  if (r == 0) {
    // ---- hist role (exact round-8 body, bid = b2, 256 roles) ----
    __shared__ unsigned hist_l[NLIST];
    for (int i = t; i < NLIST; i += 256) hist_l[i] = 0;
    __syncthreads();
    for (int n = b2 * 256 + t; n < N; n += 256 * 256)
      atomicAdd(&hist_l[db_list[n]], 1u);
    __syncthreads();
    for (int i = t; i < NLIST; i += 256)
      if (hist_l[i]) atomicAdd(&counts[i], hist_l[i]);
    return;
  }

  // ---- coarse role: cid in 0..255; query group qg = cid>>2, part = cid&3 ----
  const int cid = b2;
  const int qg = cid >> 2;
  const int part = cid & 3;
  const int q0 = qg * 4;
  __shared__ float qs4[4][DDIM];
  for (int j = t; j < 4 * DDIM; j += 256)
    qs4[j >> 7][j & 127] = queries[q0 * DDIM + j];   // rows contiguous, coalesced
  __syncthreads();
  const float qq0 = xla_sumsq128(qs4[0]);
  const float qq1 = xla_sumsq128(qs4[1]);
  const float qq2 = xla_sumsq128(qs4[2]);
  const float qq3 = xla_sumsq128(qs4[3]);
  const int c = part * 256 + t;
  const float* cr = centroids + (size_t)c * DDIM;
  float cbuf[DDIM];
  #pragma unroll
  for (int d = 0; d < DDIM; d += 4) {
    float4 cv = *(const float4*)(cr + d);
    cbuf[d] = cv.x; cbuf[d + 1] = cv.y; cbuf[d + 2] = cv.z; cbuf[d + 3] = cv.w;
  }
  const float cc = xla_sumsq128(cbuf);   // computed once, bit-exact for all 4 queries
  float dot0 = 0.f, dot1 = 0.f, dot2 = 0.f, dot3 = 0.f;
  #pragma unroll
  for (int d = 0; d < DDIM; ++d) {
    float cv = cbuf[d];
    dot0 = __fmaf_rn(qs4[0][d], cv, dot0);
    dot1 = __fmaf_rn(qs4[1][d], cv, dot1);
    dot2 = __fmaf_rn(qs4[2][d], cv, dot2);
    dot3 = __fmaf_rn(qs4[3][d], cv, dot3);
  }
  float di0 = __fsub_rn(__fadd_rn(qq0, cc), __fmul_rn(2.0f, dot0));
  float di1 = __fsub_rn(__fadd_rn(qq1, cc), __fmul_rn(2.0f, dot1));
  float di2 = __fsub_rn(__fadd_rn(qq2, cc), __fmul_rn(2.0f, dot2));
  float di3 = __fsub_rn(__fadd_rn(qq3, cc), __fmul_rn(2.0f, dot3));
  keys_g[(size_t)(q0 + 0) * NLIST + c] =
      ((unsigned long long)__float_as_uint(di0) << 32) | (unsigned)c;
  keys_g[(size_t)(q0 + 1) * NLIST + c] =
      ((unsigned long long)__float_as_uint(di1) << 32) | (unsigned)c;
  keys_g[(size_t)(q0 + 2) * NLIST + c] =
      ((unsigned long long)__float_as_uint(di2) << 32) | (unsigned)c;
  keys_g[(size_t)(q0 + 3) * NLIST + c] =
      ((unsigned long long)__float_as_uint(di3) << 32) | (unsigned)c;
}

// ------- prep: bucket scatter (nscat roles, SCHUNK=512 -> ~3 blocks/CU) +
//         per-query select/LUT (Q roles) in one 512-thread dispatch
//         (exact round-8 proven bodies).
__global__ __launch_bounds__(STHREADS) void k_prep(const float* __restrict__ queries,
                                                   const float* __restrict__ codebooks,
                                                   const unsigned long long* __restrict__ keys_g,
                                                   const int* __restrict__ db_list,
                                                   const int* __restrict__ db_codes, int N,
                                                   int Q,
                                                   const unsigned* __restrict__ counts,
                                                   unsigned* __restrict__ cursor,
                                                   int4* __restrict__ pack,
                                                   float* __restrict__ lut_g,
                                                   unsigned* __restrict__ probe_g) {
  const int t = threadIdx.x;
  const int bid = blockIdx.x;

  if (bid < Q) {
    // ---- select role: bst + LUT + coarse top-NPROBE -> probe descriptor ----
    const int qi = bid;
    __shared__ float qs[DDIM];
    __shared__ unsigned hist[HBINS];
    __shared__ unsigned long long coll[512];
    __shared__ unsigned bst[NLIST + 1];
    __shared__ unsigned pstart[NPROBE], pcum[NPROBE + 1];
    __shared__ unsigned wsum[16];
    __shared__ unsigned scnt;
    __shared__ int sT;

    if (t < DDIM) qs[t] = queries[qi * DDIM + t];
    for (int i = t; i < HBINS; i += STHREADS) hist[i] = 0;
    if (t == 0) { scnt = 0; sT = HBINS - 1; }
    const unsigned long long k0 = keys_g[(size_t)qi * NLIST + t];
    const unsigned long long k1 = keys_g[(size_t)qi * NLIST + t + STHREADS];
    {
      unsigned c0 = counts[2 * t], c1 = counts[2 * t + 1];
      unsigned s2 = c0 + c1;
      unsigned incl = block_scan_incl(s2, wsum, t, STHREADS / 64);
      bst[2 * t + 1] = incl - c1;
      bst[2 * t + 2] = incl;
      if (t == 0) bst[0] = 0;
    }
    __syncthreads();

    #pragma unroll
    for (int j = 0; j < (MSUB * KCODE) / STHREADS; ++j) {
      int idx = j * STHREADS + t;
      const float* cb = codebooks + (size_t)idx * DSUB;
      const float* qsub = qs + (idx >> 8) * DSUB;  // KCODE == 256
      float cbv[DSUB], qv[DSUB];
      #pragma unroll
      for (int d = 0; d < DSUB; d += 4) {
        float4 cv = *(const float4*)(cb + d);
        cbv[d] = cv.x; cbv[d + 1] = cv.y; cbv[d + 2] = cv.z; cbv[d + 3] = cv.w;
      }
      #pragma unroll
      for (int d = 0; d < DSUB; ++d) qv[d] = qsub[d];
      const float qq16 = xla_sumsq16(qv);
      const float cc16 = xla_sumsq16(cbv);
      const float dot16 = chain_dot16(qv, cbv);
      lut_g[(size_t)qi * (MSUB * KCODE) + idx] =
          __fsub_rn(__fadd_rn(qq16, cc16), __fmul_rn(2.0f, dot16));
    }

    atomicAdd(&hist[(unsigned)(k0 >> 51)], 1u);
    atomicAdd(&hist[(unsigned)(k1 >> 51)], 1u);
    __syncthreads();
    {
      unsigned mysum = 0;
      #pragma unroll
      for (int i = 0; i < HBINS / STHREADS; ++i) mysum += hist[t * (HBINS / STHREADS) + i];
      unsigned incl = block_scan_incl(mysum, wsum, t, STHREADS / 64);
      unsigned excl = incl - mysum;
      if (excl < NPROBE && NPROBE <= incl) {
        unsigned c2 = excl;
        #pragma unroll
        for (int i = 0; i < HBINS / STHREADS; ++i) {
          unsigned h = hist[t * (HBINS / STHREADS) + i];
          if (c2 + h >= NPROBE) { sT = t * (HBINS / STHREADS) + i; break; }
          c2 += h;
        }
      }
    }
    __syncthreads();
    {
      const int T32 = sT;
      if ((int)(k0 >> 51) <= T32) {
        unsigned p = atomicAdd(&scnt, 1u);
        if (p < 512) coll[p] = k0;
      }
      if ((int)(k1 >> 51) <= T32) {
        unsigned p = atomicAdd(&scnt, 1u);
        if (p < 512) coll[p] = k1;
      }
    }
    __syncthreads();
    {
      unsigned cnt = scnt; if (cnt > 512) cnt = 512;
      for (unsigned i = t; i < cnt; i += STHREADS) {
        unsigned long long k2 = coll[i];
        unsigned r = 0;
        for (unsigned j = 0; j < cnt; ++j) r += (coll[j] < k2) ? 1u : 0u;
        if (r < NPROBE) {
          unsigned l = (unsigned)(k2 & 0xffffffffULL);
          pstart[r] = bst[l];
          pcum[r + 1] = bst[l + 1] - bst[l];
        }
      }
    }
    __syncthreads();
    if (t == 0) {
      unsigned acc = 0;
      pcum[0] = 0;
      for (int j = 1; j <= NPROBE; ++j) { acc += pcum[j]; pcum[j] = acc; }
    }
    __syncthreads();
    if (t < NPROBE)     probe_g[qi * PSTRIDE + t] = pstart[t];
    if (t < NPROBE + 1) probe_g[qi * PSTRIDE + NPROBE + t] = pcum[t];
    return;
  }

  // ---- scatter role (exact round-8 body; chunk = bid - Q, SCHUNK = 512) ----
  __shared__ unsigned lhist[NLIST], lbase[NLIST], sbstart[NLIST];
  __shared__ unsigned wsum2[16];
  const int base = (bid - Q) * SCHUNK;
  {
    unsigned c0 = counts[t * 2], c1 = counts[t * 2 + 1];
    unsigned sum2 = c0 + c1;
    unsigned incl = block_scan_incl(sum2, wsum2, t, STHREADS / 64);
    unsigned excl = incl - sum2;
    sbstart[t * 2] = excl;
    sbstart[t * 2 + 1] = excl + c0;
  }
  for (int i = t; i < NLIST; i += STHREADS) lhist[i] = 0;
  __syncthreads();
  #pragma unroll
  for (int k = 0; k < SCHUNK / STHREADS; ++k) {
    int n = base + k * STHREADS + t;
    if (n < N) atomicAdd(&lhist[db_list[n]], 1u);
  }
  __syncthreads();
  for (int i = t; i < NLIST; i += STHREADS) {
    unsigned cnt = lhist[i];
    if (cnt) lbase[i] = sbstart[i] + atomicAdd(&cursor[i], cnt);
    lhist[i] = 0;
  }
  __syncthreads();
  #pragma unroll
  for (int k = 0; k < SCHUNK / STHREADS; ++k) {
    int n = base + k * STHREADS + t;
    if (n < N) {
      int l = db_list[n];
      unsigned pos = lbase[l] + atomicAdd(&lhist[l], 1u);
      const int4* cp = (const int4*)(db_codes + (size_t)n * MSUB);
      int4 c0 = cp[0], c1 = cp[1];
      unsigned lo = (unsigned)(c0.x & 255) | ((unsigned)(c0.y & 255) << 8) |
                    ((unsigned)(c0.z & 255) << 16) | ((unsigned)(c0.w & 255) << 24);
      unsigned hi = (unsigned)(c1.x & 255) | ((unsigned)(c1.y & 255) << 8) |
                    ((unsigned)(c1.z & 255) << 16) | ((unsigned)(c1.w & 255) << 24);
      pack[pos] = make_int4((int)lo, (int)hi, n, 0);
    }
  }
}

// ---------------- search: ADC + top-k only (prologue precomputed in k_prep) ----
__global__ __launch_bounds__(1024, 1) void k_search(const float* __restrict__ lut_g,
                                                    const unsigned* __restrict__ probe_g,
                                                    const int4* __restrict__ pack,
                                                    int* __restrict__ out) {
  const int qi = blockIdx.x;
  const int t = threadIdx.x;
  __shared__ float lut_s[MSUB * KCODE];
  __shared__ unsigned hist[HBINS];
  __shared__ unsigned long long coll[COLL_CAP];
  __shared__ unsigned pstart[NPROBE], pcum[NPROBE + 1];
  __shared__ unsigned wsum[16];
  __shared__ unsigned scnt;
  __shared__ int sT;

  lut_s[t] = lut_g[(size_t)qi * (MSUB * KCODE) + t];
  lut_s[1024 + t] = lut_g[(size_t)qi * (MSUB * KCODE) + 1024 + t];
  for (int i = t; i < HBINS; i += 1024) hist[i] = 0;
  if (t < NPROBE)     pstart[t] = probe_g[qi * PSTRIDE + t];
  if (t < NPROBE + 1) pcum[t] = probe_g[qi * PSTRIDE + NPROBE + t];
  if (t == 0) { scnt = 0; sT = HBINS - 1; }
  __syncthreads();
  const unsigned total = pcum[NPROBE];

  // ---- pass 1: ADC once, keys in STATICALLY-indexed registers,
  //      probe lookup via monotonic walk (g strictly increases per thread) ----
  unsigned long long regkey[RCAP];
  int lo = 0;
  #pragma unroll
  for (int s = 0; s < RCAP; ++s) {
    unsigned g = (unsigned)t + (unsigned)(s * 1024);
    if (g < total) {
      while (pcum[lo + 1] <= g) ++lo;
      unsigned addr = pstart[lo] + (g - pcum[lo]);
      int4 w = pack[addr];
      unsigned long long code = (unsigned)w.x | ((unsigned long long)(unsigned)w.y << 32);
      unsigned bits = __float_as_uint(adc_dist(lut_s, code));
      regkey[s] = ((unsigned long long)bits << 32) | (unsigned)w.z;
      atomicAdd(&hist[bits >> 19], 1u);
    }
  }
  // defensive tail (never taken at this problem size: RCAP*1024 = 10240 > max total)
  for (unsigned g = (unsigned)t + RCAP * 1024; g < total; g += 1024) {
    while (pcum[lo + 1] <= g) ++lo;
    unsigned addr = pstart[lo] + (g - pcum[lo]);
    int4 w = pack[addr];
    unsigned long long code = (unsigned)w.x | ((unsigned long long)(unsigned)w.y << 32);
    unsigned bits = __float_as_uint(adc_dist(lut_s, code));
    atomicAdd(&hist[bits >> 19], 1u);
  }
  __syncthreads();

  // ---- find T = bin containing rank TOPK ----
  {
    unsigned mysum = 0;
    #pragma unroll
    for (int i = 0; i < 4; ++i) mysum += hist[t * 4 + i];
    unsigned incl = block_scan_incl(mysum, wsum, t, 16);
    unsigned excl = incl - mysum;
    if (excl < TOPK && TOPK <= incl) {
      unsigned c = excl;
      #pragma unroll
      for (int i = 0; i < 4; ++i) {
        unsigned h = hist[t * 4 + i];
        if (c + h >= TOPK) { sT = t * 4 + i; break; }
        c += h;
      }
    }
  }
  __syncthreads();
  const int T = sT;

  // ---- pass 2: collect ALL candidates with bin <= T (register replay) ----
  {
    #pragma unroll
    for (int s = 0; s < RCAP; ++s) {
      unsigned g = (unsigned)t + (unsigned)(s * 1024);
      if (g < total) {
        unsigned long long k2 = regkey[s];
        if ((int)(unsigned)(k2 >> 51) <= T) {   // == bits >> 19
          unsigned p = atomicAdd(&scnt, 1u);
          if (p < COLL_CAP) coll[p] = k2;
        }
      }
    }
    int lo2 = 0;
    for (unsigned g = (unsigned)t + RCAP * 1024; g < total; g += 1024) {
      while (pcum[lo2 + 1] <= g) ++lo2;
      unsigned addr = pstart[lo2] + (g - pcum[lo2]);
      int4 w = pack[addr];
      unsigned long long code = (unsigned)w.x | ((unsigned long long)(unsigned)w.y << 32);
      unsigned bits = __float_as_uint(adc_dist(lut_s, code));
      if ((int)(bits >> 19) <= T) {
        unsigned p = atomicAdd(&scnt, 1u);
        if (p < COLL_CAP) coll[p] = ((unsigned long long)bits << 32) | (unsigned)w.z;
      }
    }
  }
  __syncthreads();

  // ---- exact rank by (fp32 bits, index) ----
  unsigned cnt = scnt;
  if (cnt > COLL_CAP) cnt = COLL_CAP;
  for (unsigned i = t; i < cnt; i += 1024) {
    unsigned long long key = coll[i];
    unsigned r = 0;
    for (unsigned j = 0; j < cnt; ++j) r += (coll[j] < key) ? 1u : 0u;
    if (r < TOPK) out[qi * TOPK + r] = (int)(key & 0xffffffffULL);
  }
}

extern "C" void kernel_launch(void* const* d_in, const int* in_sizes, int n_in,
                              void* d_out, int out_size, void* d_ws, size_t ws_size,
                              hipStream_t stream) {
  const float* queries   = (const float*)d_in[0];
  const float* centroids = (const float*)d_in[1];
  const float* codebooks = (const float*)d_in[2];
  const int*   db_codes  = (const int*)d_in[3];
  const int*   db_list   = (const int*)d_in[4];
  const int N = in_sizes[4];
  const int Q = in_sizes[0] / DDIM;
  int* out = (int*)d_out;

  char* p = (char*)d_ws;
  unsigned long long* keys_g = (unsigned long long*)p; p += (size_t)Q * NLIST * 8;
  unsigned* counts = (unsigned*)p;                  p += NLIST * 4;
  unsigned* cursor = (unsigned*)p;                  p += NLIST * 4;
  int4* pack = (int4*)p;                            p += (size_t)N * 16;
  float* lut_g = (float*)p;                         p += (size_t)Q * MSUB * KCODE * 4;
  unsigned* probe_g = (unsigned*)p;                 p += (size_t)Q * PSTRIDE * 4;

  const int nscat = (N + SCHUNK - 1) / SCHUNK;

  hipMemsetAsync(counts, 0, (size_t)NLIST * 4 * 2, stream); // counts + cursor

  // 512 blocks: 256 hist roles + 256 four-query coarse roles (Q/4 groups * 4 parts)
  k_front<<<512, 256, 0, stream>>>(queries, centroids, db_list, N, keys_g, counts);
  k_prep<<<Q + nscat, STHREADS, 0, stream>>>(queries, codebooks, keys_g, db_list,
                                             db_codes, N, Q, counts, cursor, pack,
                                             lut_g, probe_g);
  k_search<<<Q, 1024, 0, stream>>>(lut_g, probe_g, pack, out);
}

// Round 12
// 120.882 us; speedup vs baseline: 1.1823x; 1.1823x over previous
//
#include <hip/hip_runtime.h>

#define DDIM 128
#define MSUB 8
#define KCODE 256
#define DSUB 16
#define NLIST 1024
#define NPROBE 32
#define TOPK 100
#define HBINS 4096
#define COLL_CAP 2048
#define RCAP 10
#define SCHUNK 512
#define STHREADS 512
#define PSTRIDE 66   // per-query probe descriptor: 32 pstart + 33 pcum

// ==== FROZEN ARITHMETIC (bit-exact vs reference — do not modify) ====

__device__ __forceinline__ float xla_sumsq128(const float* x) {
  float s[16];
  #pragma unroll
  for (int j = 0; j < 16; ++j) {
    float p0 = __fmul_rn(x[j],       x[j]);
    float p1 = __fmul_rn(x[j + 16],  x[j + 16]);
    float p2 = __fmul_rn(x[j + 32],  x[j + 32]);
    float p3 = __fmul_rn(x[j + 48],  x[j + 48]);
    float p4 = __fmul_rn(x[j + 64],  x[j + 64]);
    float p5 = __fmul_rn(x[j + 80],  x[j + 80]);
    float p6 = __fmul_rn(x[j + 96],  x[j + 96]);
    float p7 = __fmul_rn(x[j + 112], x[j + 112]);
    float r0 = __fadd_rn(p0, p4);
    float r1 = __fadd_rn(p1, p5);
    float r2 = __fadd_rn(p2, p6);
    float r3 = __fadd_rn(p3, p7);
    s[j] = __fadd_rn(__fadd_rn(r0, r1), __fadd_rn(r2, r3));
  }
  float a[8], b[4], c[2];
  #pragma unroll
  for (int j = 0; j < 8; ++j) a[j] = __fadd_rn(s[j], s[j + 8]);
  #pragma unroll
  for (int j = 0; j < 4; ++j) b[j] = __fadd_rn(a[j], a[j + 4]);
  #pragma unroll
  for (int j = 0; j < 2; ++j) c[j] = __fadd_rn(b[j], b[j + 2]);
  return __fadd_rn(c[0], c[1]);
}

__device__ __forceinline__ float xla_sumsq16(const float* x) {
  float p[16];
  #pragma unroll
  for (int j = 0; j < 16; ++j) p[j] = __fmul_rn(x[j], x[j]);
  float s8[8], s4[4], s2[2];
  #pragma unroll
  for (int j = 0; j < 8; ++j) s8[j] = __fadd_rn(p[j], p[j + 8]);
  #pragma unroll
  for (int j = 0; j < 4; ++j) s4[j] = __fadd_rn(s8[j], s8[j + 4]);
  #pragma unroll
  for (int j = 0; j < 2; ++j) s2[j] = __fadd_rn(s4[j], s4[j + 2]);
  return __fadd_rn(s2[0], s2[1]);
}

__device__ __forceinline__ float chain_dot16(const float* a, const float* b) {
  float dot = 0.f;
  #pragma unroll
  for (int d = 0; d < DSUB; ++d) dot = __fmaf_rn(a[d], b[d], dot);
  return dot;
}

__device__ __forceinline__ float adc_dist(const float* lut, unsigned long long code) {
  float d = lut[(unsigned)(code & 255ULL)];
  d = __fadd_rn(d, lut[256  + (unsigned)((code >> 8)  & 255ULL)]);
  d = __fadd_rn(d, lut[512  + (unsigned)((code >> 16) & 255ULL)]);
  d = __fadd_rn(d, lut[768  + (unsigned)((code >> 24) & 255ULL)]);
  d = __fadd_rn(d, lut[1024 + (unsigned)((code >> 32) & 255ULL)]);
  d = __fadd_rn(d, lut[1280 + (unsigned)((code >> 40) & 255ULL)]);
  d = __fadd_rn(d, lut[1536 + (unsigned)((code >> 48) & 255ULL)]);
  d = __fadd_rn(d, lut[1792 + (unsigned)((code >> 56) & 255ULL)]);
  return d;
}

// ==== helpers ====
__device__ __forceinline__ unsigned block_scan_incl(unsigned v, volatile unsigned* wsum,
                                                    int t, int nwaves) {
  int lane = t & 63, wid = t >> 6;
  #pragma unroll
  for (int off = 1; off < 64; off <<= 1) {
    unsigned u = __shfl_up(v, off, 64);
    if (lane >= off) v += u;
  }
  if (lane == 63) wsum[wid] = v;
  __syncthreads();
  if (wid == 0 && lane < nwaves) {
    unsigned wv = wsum[lane];
    #pragma unroll
    for (int off = 1; off < 16; off <<= 1) {
      unsigned u = __shfl_up(wv, off, 64);
      if (lane >= off) wv += u;
    }
    wsum[lane] = wv;
  }
  __syncthreads();
  return v + (wid > 0 ? wsum[wid - 1] : 0u);
}

// ------- front: 2-query coarse roles (512) + LDS-aggregated db_list hist roles
//         (256, exact R8 body), interleaved bid%3 over a 768-block grid.
//         (exact round-10 proven body: 152 VGPR, no spill — 4-query variant
//         hit the 256-VGPR cliff in R11, do not revisit)
__global__ __launch_bounds__(256) void k_front(const float* __restrict__ queries,
                                               const float* __restrict__ centroids,
                                               const int* __restrict__ db_list, int N,
                                               unsigned long long* __restrict__ keys_g,
                                               unsigned* __restrict__ counts) {
  const int t = threadIdx.x;
  const int r  = blockIdx.x % 3;
  const int b3 = blockIdx.x / 3;

  if (r == 0) {
    // ---- hist role (exact round-8 body, bid = b3, 256 roles) ----
    __shared__ unsigned hist_l[NLIST];
    for (int i = t; i < NLIST; i += 256) hist_l[i] = 0;
    __syncthreads();
    for (int n = b3 * 256 + t; n < N; n += 256 * 256)
      atomicAdd(&hist_l[db_list[n]], 1u);
    __syncthreads();
    for (int i = t; i < NLIST; i += 256)
      if (hist_l[i]) atomicAdd(&counts[i], hist_l[i]);
    return;
  }

  // ---- coarse role: cid in 0..511; query pair qg = cid>>2, part = cid&3 ----
  const int cid = b3 * 2 + (r - 1);
  const int qg = cid >> 2;
  const int part = cid & 3;
  const int qa = qg * 2, qb = qg * 2 + 1;
  __shared__ float qsa[DDIM], qsb[DDIM];
  if (t < DDIM) {
    qsa[t] = queries[qa * DDIM + t];
    qsb[t] = queries[qb * DDIM + t];
  }
  __syncthreads();
  const float qqa = xla_sumsq128(qsa);
  const float qqb = xla_sumsq128(qsb);
  const int c = part * 256 + t;
  const float* cr = centroids + (size_t)c * DDIM;
  float cbuf[DDIM];
  #pragma unroll
  for (int d = 0; d < DDIM; d += 4) {
    float4 cv = *(const float4*)(cr + d);
    cbuf[d] = cv.x; cbuf[d + 1] = cv.y; cbuf[d + 2] = cv.z; cbuf[d + 3] = cv.w;
  }
  const float cc = xla_sumsq128(cbuf);   // computed once, bit-exact for both queries
  float dota = 0.f, dotb = 0.f;
  #pragma unroll
  for (int d = 0; d < DDIM; ++d) {
    dota = __fmaf_rn(qsa[d], cbuf[d], dota);
    dotb = __fmaf_rn(qsb[d], cbuf[d], dotb);
  }
  float dista = __fsub_rn(__fadd_rn(qqa, cc), __fmul_rn(2.0f, dota));
  float distb = __fsub_rn(__fadd_rn(qqb, cc), __fmul_rn(2.0f, dotb));
  keys_g[(size_t)qa * NLIST + c] =
      ((unsigned long long)__float_as_uint(dista) << 32) | (unsigned)c;
  keys_g[(size_t)qb * NLIST + c] =
      ((unsigned long long)__float_as_uint(distb) << 32) | (unsigned)c;
}

// ------- prep: bucket scatter (nscat roles, SCHUNK=512 -> ~3 blocks/CU) +
//         per-query select/LUT (Q roles) in one 512-thread dispatch
//         (exact round-8 proven bodies; SCHUNK is this round's single variable).
__global__ __launch_bounds__(STHREADS) void k_prep(const float* __restrict__ queries,
                                                   const float* __restrict__ codebooks,
                                                   const unsigned long long* __restrict__ keys_g,
                                                   const int* __restrict__ db_list,
                                                   const int* __restrict__ db_codes, int N,
                                                   int Q,
                                                   const unsigned* __restrict__ counts,
                                                   unsigned* __restrict__ cursor,
                                                   int4* __restrict__ pack,
                                                   float* __restrict__ lut_g,
                                                   unsigned* __restrict__ probe_g) {
  const int t = threadIdx.x;
  const int bid = blockIdx.x;

  if (bid < Q) {
    // ---- select role: bst + LUT + coarse top-NPROBE -> probe descriptor ----
    const int qi = bid;
    __shared__ float qs[DDIM];
    __shared__ unsigned hist[HBINS];
    __shared__ unsigned long long coll[512];
    __shared__ unsigned bst[NLIST + 1];
    __shared__ unsigned pstart[NPROBE], pcum[NPROBE + 1];
    __shared__ unsigned wsum[16];
    __shared__ unsigned scnt;
    __shared__ int sT;

    if (t < DDIM) qs[t] = queries[qi * DDIM + t];
    for (int i = t; i < HBINS; i += STHREADS) hist[i] = 0;
    if (t == 0) { scnt = 0; sT = HBINS - 1; }
    const unsigned long long k0 = keys_g[(size_t)qi * NLIST + t];
    const unsigned long long k1 = keys_g[(size_t)qi * NLIST + t + STHREADS];
    {
      unsigned c0 = counts[2 * t], c1 = counts[2 * t + 1];
      unsigned s2 = c0 + c1;
      unsigned incl = block_scan_incl(s2, wsum, t, STHREADS / 64);
      bst[2 * t + 1] = incl - c1;
      bst[2 * t + 2] = incl;
      if (t == 0) bst[0] = 0;
    }
    __syncthreads();

    #pragma unroll
    for (int j = 0; j < (MSUB * KCODE) / STHREADS; ++j) {
      int idx = j * STHREADS + t;
      const float* cb = codebooks + (size_t)idx * DSUB;
      const float* qsub = qs + (idx >> 8) * DSUB;  // KCODE == 256
      float cbv[DSUB], qv[DSUB];
      #pragma unroll
      for (int d = 0; d < DSUB; d += 4) {
        float4 cv = *(const float4*)(cb + d);
        cbv[d] = cv.x; cbv[d + 1] = cv.y; cbv[d + 2] = cv.z; cbv[d + 3] = cv.w;
      }
      #pragma unroll
      for (int d = 0; d < DSUB; ++d) qv[d] = qsub[d];
      const float qq16 = xla_sumsq16(qv);
      const float cc16 = xla_sumsq16(cbv);
      const float dot16 = chain_dot16(qv, cbv);
      lut_g[(size_t)qi * (MSUB * KCODE) + idx] =
          __fsub_rn(__fadd_rn(qq16, cc16), __fmul_rn(2.0f, dot16));
    }

    atomicAdd(&hist[(unsigned)(k0 >> 51)], 1u);
    atomicAdd(&hist[(unsigned)(k1 >> 51)], 1u);
    __syncthreads();
    {
      unsigned mysum = 0;
      #pragma unroll
      for (int i = 0; i < HBINS / STHREADS; ++i) mysum += hist[t * (HBINS / STHREADS) + i];
      unsigned incl = block_scan_incl(mysum, wsum, t, STHREADS / 64);
      unsigned excl = incl - mysum;
      if (excl < NPROBE && NPROBE <= incl) {
        unsigned c2 = excl;
        #pragma unroll
        for (int i = 0; i < HBINS / STHREADS; ++i) {
          unsigned h = hist[t * (HBINS / STHREADS) + i];
          if (c2 + h >= NPROBE) { sT = t * (HBINS / STHREADS) + i; break; }
          c2 += h;
        }
      }
    }
    __syncthreads();
    {
      const int T32 = sT;
      if ((int)(k0 >> 51) <= T32) {
        unsigned p = atomicAdd(&scnt, 1u);
        if (p < 512) coll[p] = k0;
      }
      if ((int)(k1 >> 51) <= T32) {
        unsigned p = atomicAdd(&scnt, 1u);
        if (p < 512) coll[p] = k1;
      }
    }
    __syncthreads();
    {
      unsigned cnt = scnt; if (cnt > 512) cnt = 512;
      for (unsigned i = t; i < cnt; i += STHREADS) {
        unsigned long long k2 = coll[i];
        unsigned r = 0;
        for (unsigned j = 0; j < cnt; ++j) r += (coll[j] < k2) ? 1u : 0u;
        if (r < NPROBE) {
          unsigned l = (unsigned)(k2 & 0xffffffffULL);
          pstart[r] = bst[l];
          pcum[r + 1] = bst[l + 1] - bst[l];
        }
      }
    }
    __syncthreads();
    if (t == 0) {
      unsigned acc = 0;
      pcum[0] = 0;
      for (int j = 1; j <= NPROBE; ++j) { acc += pcum[j]; pcum[j] = acc; }
    }
    __syncthreads();
    if (t < NPROBE)     probe_g[qi * PSTRIDE + t] = pstart[t];
    if (t < NPROBE + 1) probe_g[qi * PSTRIDE + NPROBE + t] = pcum[t];
    return;
  }

  // ---- scatter role (exact round-8 body; chunk = bid - Q, SCHUNK = 512) ----
  __shared__ unsigned lhist[NLIST], lbase[NLIST], sbstart[NLIST];
  __shared__ unsigned wsum2[16];
  const int base = (bid - Q) * SCHUNK;
  {
    unsigned c0 = counts[t * 2], c1 = counts[t * 2 + 1];
    unsigned sum2 = c0 + c1;
    unsigned incl = block_scan_incl(sum2, wsum2, t, STHREADS / 64);
    unsigned excl = incl - sum2;
    sbstart[t * 2] = excl;
    sbstart[t * 2 + 1] = excl + c0;
  }
  for (int i = t; i < NLIST; i += STHREADS) lhist[i] = 0;
  __syncthreads();
  #pragma unroll
  for (int k = 0; k < SCHUNK / STHREADS; ++k) {
    int n = base + k * STHREADS + t;
    if (n < N) atomicAdd(&lhist[db_list[n]], 1u);
  }
  __syncthreads();
  for (int i = t; i < NLIST; i += STHREADS) {
    unsigned cnt = lhist[i];
    if (cnt) lbase[i] = sbstart[i] + atomicAdd(&cursor[i], cnt);
    lhist[i] = 0;
  }
  __syncthreads();
  #pragma unroll
  for (int k = 0; k < SCHUNK / STHREADS; ++k) {
    int n = base + k * STHREADS + t;
    if (n < N) {
      int l = db_list[n];
      unsigned pos = lbase[l] + atomicAdd(&lhist[l], 1u);
      const int4* cp = (const int4*)(db_codes + (size_t)n * MSUB);
      int4 c0 = cp[0], c1 = cp[1];
      unsigned lo = (unsigned)(c0.x & 255) | ((unsigned)(c0.y & 255) << 8) |
                    ((unsigned)(c0.z & 255) << 16) | ((unsigned)(c0.w & 255) << 24);
      unsigned hi = (unsigned)(c1.x & 255) | ((unsigned)(c1.y & 255) << 8) |
                    ((unsigned)(c1.z & 255) << 16) | ((unsigned)(c1.w & 255) << 24);
      pack[pos] = make_int4((int)lo, (int)hi, n, 0);
    }
  }
}

// ---------------- search: ADC + top-k only (prologue precomputed in k_prep) ----
__global__ __launch_bounds__(1024, 1) void k_search(const float* __restrict__ lut_g,
                                                    const unsigned* __restrict__ probe_g,
                                                    const int4* __restrict__ pack,
                                                    int* __restrict__ out) {
  const int qi = blockIdx.x;
  const int t = threadIdx.x;
  __shared__ float lut_s[MSUB * KCODE];
  __shared__ unsigned hist[HBINS];
  __shared__ unsigned long long coll[COLL_CAP];
  __shared__ unsigned pstart[NPROBE], pcum[NPROBE + 1];
  __shared__ unsigned wsum[16];
  __shared__ unsigned scnt;
  __shared__ int sT;

  lut_s[t] = lut_g[(size_t)qi * (MSUB * KCODE) + t];
  lut_s[1024 + t] = lut_g[(size_t)qi * (MSUB * KCODE) + 1024 + t];
  for (int i = t; i < HBINS; i += 1024) hist[i] = 0;
  if (t < NPROBE)     pstart[t] = probe_g[qi * PSTRIDE + t];
  if (t < NPROBE + 1) pcum[t] = probe_g[qi * PSTRIDE + NPROBE + t];
  if (t == 0) { scnt = 0; sT = HBINS - 1; }
  __syncthreads();
  const unsigned total = pcum[NPROBE];

  // ---- pass 1: ADC once, keys in STATICALLY-indexed registers,
  //      probe lookup via monotonic walk (g strictly increases per thread) ----
  unsigned long long regkey[RCAP];
  int lo = 0;
  #pragma unroll
  for (int s = 0; s < RCAP; ++s) {
    unsigned g = (unsigned)t + (unsigned)(s * 1024);
    if (g < total) {
      while (pcum[lo + 1] <= g) ++lo;
      unsigned addr = pstart[lo] + (g - pcum[lo]);
      int4 w = pack[addr];
      unsigned long long code = (unsigned)w.x | ((unsigned long long)(unsigned)w.y << 32);
      unsigned bits = __float_as_uint(adc_dist(lut_s, code));
      regkey[s] = ((unsigned long long)bits << 32) | (unsigned)w.z;
      atomicAdd(&hist[bits >> 19], 1u);
    }
  }
  // defensive tail (never taken at this problem size: RCAP*1024 = 10240 > max total)
  for (unsigned g = (unsigned)t + RCAP * 1024; g < total; g += 1024) {
    while (pcum[lo + 1] <= g) ++lo;
    unsigned addr = pstart[lo] + (g - pcum[lo]);
    int4 w = pack[addr];
    unsigned long long code = (unsigned)w.x | ((unsigned long long)(unsigned)w.y << 32);
    unsigned bits = __float_as_uint(adc_dist(lut_s, code));
    atomicAdd(&hist[bits >> 19], 1u);
  }
  __syncthreads();

  // ---- find T = bin containing rank TOPK ----
  {
    unsigned mysum = 0;
    #pragma unroll
    for (int i = 0; i < 4; ++i) mysum += hist[t * 4 + i];
    unsigned incl = block_scan_incl(mysum, wsum, t, 16);
    unsigned excl = incl - mysum;
    if (excl < TOPK && TOPK <= incl) {
      unsigned c = excl;
      #pragma unroll
      for (int i = 0; i < 4; ++i) {
        unsigned h = hist[t * 4 + i];
        if (c + h >= TOPK) { sT = t * 4 + i; break; }
        c += h;
      }
    }
  }
  __syncthreads();
  const int T = sT;

  // ---- pass 2: collect ALL candidates with bin <= T (register replay) ----
  {
    #pragma unroll
    for (int s = 0; s < RCAP; ++s) {
      unsigned g = (unsigned)t + (unsigned)(s * 1024);
      if (g < total) {
        unsigned long long k2 = regkey[s];
        if ((int)(unsigned)(k2 >> 51) <= T) {   // == bits >> 19
          unsigned p = atomicAdd(&scnt, 1u);
          if (p < COLL_CAP) coll[p] = k2;
        }
      }
    }
    int lo2 = 0;
    for (unsigned g = (unsigned)t + RCAP * 1024; g < total; g += 1024) {
      while (pcum[lo2 + 1] <= g) ++lo2;
      unsigned addr = pstart[lo2] + (g - pcum[lo2]);
      int4 w = pack[addr];
      unsigned long long code = (unsigned)w.x | ((unsigned long long)(unsigned)w.y << 32);
      unsigned bits = __float_as_uint(adc_dist(lut_s, code));
      if ((int)(bits >> 19) <= T) {
        unsigned p = atomicAdd(&scnt, 1u);
        if (p < COLL_CAP) coll[p] = ((unsigned long long)bits << 32) | (unsigned)w.z;
      }
    }
  }
  __syncthreads();

  // ---- exact rank by (fp32 bits, index) ----
  unsigned cnt = scnt;
  if (cnt > COLL_CAP) cnt = COLL_CAP;
  for (unsigned i = t; i < cnt; i += 1024) {
    unsigned long long key = coll[i];
    unsigned r = 0;
    for (unsigned j = 0; j < cnt; ++j) r += (coll[j] < key) ? 1u : 0u;
    if (r < TOPK) out[qi * TOPK + r] = (int)(key & 0xffffffffULL);
  }
}

extern "C" void kernel_launch(void* const* d_in, const int* in_sizes, int n_in,
                              void* d_out, int out_size, void* d_ws, size_t ws_size,
                              hipStream_t stream) {
  const float* queries   = (const float*)d_in[0];
  const float* centroids = (const float*)d_in[1];
  const float* codebooks = (const float*)d_in[2];
  const int*   db_codes  = (const int*)d_in[3];
  const int*   db_list   = (const int*)d_in[4];
  const int N = in_sizes[4];
  const int Q = in_sizes[0] / DDIM;
  int* out = (int*)d_out;

  char* p = (char*)d_ws;
  unsigned long long* keys_g = (unsigned long long*)p; p += (size_t)Q * NLIST * 8;
  unsigned* counts = (unsigned*)p;                  p += NLIST * 4;
  unsigned* cursor = (unsigned*)p;                  p += NLIST * 4;
  int4* pack = (int4*)p;                            p += (size_t)N * 16;
  float* lut_g = (float*)p;                         p += (size_t)Q * MSUB * KCODE * 4;
  unsigned* probe_g = (unsigned*)p;                 p += (size_t)Q * PSTRIDE * 4;

  const int nscat = (N + SCHUNK - 1) / SCHUNK;

  hipMemsetAsync(counts, 0, (size_t)NLIST * 4 * 2, stream); // counts + cursor

  // 768 blocks: 256 hist roles + 512 two-query coarse roles (Q/2 * 4 parts)
  k_front<<<768, 256, 0, stream>>>(queries, centroids, db_list, N, keys_g, counts);
  k_prep<<<Q + nscat, STHREADS, 0, stream>>>(queries, codebooks, keys_g, db_list,
                                             db_codes, N, Q, counts, cursor, pack,
                                             lut_g, probe_g);
  k_search<<<Q, 1024, 0, stream>>>(lut_g, probe_g, pack, out);
}

// Round 13
// 114.630 us; speedup vs baseline: 1.2468x; 1.0545x over previous
//
#include <hip/hip_runtime.h>

#define DDIM 128
#define MSUB 8
#define KCODE 256
#define DSUB 16
#define NLIST 1024
#define NPROBE 32
#define TOPK 100
#define HBINS 4096
#define COLL_CAP 2048
#define RCAP 10
#define SCHUNK 1024
#define STHREADS 512
#define PSTRIDE 66   // per-query probe descriptor: 32 pstart + 33 pcum

// ==== FROZEN ARITHMETIC (bit-exact vs reference — do not modify) ====

__device__ __forceinline__ float xla_sumsq128(const float* x) {
  float s[16];
  #pragma unroll
  for (int j = 0; j < 16; ++j) {
    float p0 = __fmul_rn(x[j],       x[j]);
    float p1 = __fmul_rn(x[j + 16],  x[j + 16]);
    float p2 = __fmul_rn(x[j + 32],  x[j + 32]);
    float p3 = __fmul_rn(x[j + 48],  x[j + 48]);
    float p4 = __fmul_rn(x[j + 64],  x[j + 64]);
    float p5 = __fmul_rn(x[j + 80],  x[j + 80]);
    float p6 = __fmul_rn(x[j + 96],  x[j + 96]);
    float p7 = __fmul_rn(x[j + 112], x[j + 112]);
    float r0 = __fadd_rn(p0, p4);
    float r1 = __fadd_rn(p1, p5);
    float r2 = __fadd_rn(p2, p6);
    float r3 = __fadd_rn(p3, p7);
    s[j] = __fadd_rn(__fadd_rn(r0, r1), __fadd_rn(r2, r3));
  }
  float a[8], b[4], c[2];
  #pragma unroll
  for (int j = 0; j < 8; ++j) a[j] = __fadd_rn(s[j], s[j + 8]);
  #pragma unroll
  for (int j = 0; j < 4; ++j) b[j] = __fadd_rn(a[j], a[j + 4]);
  #pragma unroll
  for (int j = 0; j < 2; ++j) c[j] = __fadd_rn(b[j], b[j + 2]);
  return __fadd_rn(c[0], c[1]);
}

__device__ __forceinline__ float xla_sumsq16(const float* x) {
  float p[16];
  #pragma unroll
  for (int j = 0; j < 16; ++j) p[j] = __fmul_rn(x[j], x[j]);
  float s8[8], s4[4], s2[2];
  #pragma unroll
  for (int j = 0; j < 8; ++j) s8[j] = __fadd_rn(p[j], p[j + 8]);
  #pragma unroll
  for (int j = 0; j < 4; ++j) s4[j] = __fadd_rn(s8[j], s8[j + 4]);
  #pragma unroll
  for (int j = 0; j < 2; ++j) s2[j] = __fadd_rn(s4[j], s4[j + 2]);
  return __fadd_rn(s2[0], s2[1]);
}

__device__ __forceinline__ float chain_dot16(const float* a, const float* b) {
  float dot = 0.f;
  #pragma unroll
  for (int d = 0; d < DSUB; ++d) dot = __fmaf_rn(a[d], b[d], dot);
  return dot;
}

__device__ __forceinline__ float adc_dist(const float* lut, unsigned long long code) {
  float d = lut[(unsigned)(code & 255ULL)];
  d = __fadd_rn(d, lut[256  + (unsigned)((code >> 8)  & 255ULL)]);
  d = __fadd_rn(d, lut[512  + (unsigned)((code >> 16) & 255ULL)]);
  d = __fadd_rn(d, lut[768  + (unsigned)((code >> 24) & 255ULL)]);
  d = __fadd_rn(d, lut[1024 + (unsigned)((code >> 32) & 255ULL)]);
  d = __fadd_rn(d, lut[1280 + (unsigned)((code >> 40) & 255ULL)]);
  d = __fadd_rn(d, lut[1536 + (unsigned)((code >> 48) & 255ULL)]);
  d = __fadd_rn(d, lut[1792 + (unsigned)((code >> 56) & 255ULL)]);
  return d;
}

// ==== helpers ====
__device__ __forceinline__ unsigned block_scan_incl(unsigned v, volatile unsigned* wsum,
                                                    int t, int nwaves) {
  int lane = t & 63, wid = t >> 6;
  #pragma unroll
  for (int off = 1; off < 64; off <<= 1) {
    unsigned u = __shfl_up(v, off, 64);
    if (lane >= off) v += u;
  }
  if (lane == 63) wsum[wid] = v;
  __syncthreads();
  if (wid == 0 && lane < nwaves) {
    unsigned wv = wsum[lane];
    #pragma unroll
    for (int off = 1; off < 16; off <<= 1) {
      unsigned u = __shfl_up(wv, off, 64);
      if (lane >= off) wv += u;
    }
    wsum[lane] = wv;
  }
  __syncthreads();
  return v + (wid > 0 ? wsum[wid - 1] : 0u);
}

// ------- front: 2-query coarse roles (512) + LDS-aggregated db_list hist roles
//         (256, exact R8 body), interleaved bid%3 over a 768-block grid.
//         (exact round-10 proven body: 152 VGPR, no spill — 4-query variant
//         hit the 256-VGPR cliff in R11, do not revisit)
__global__ __launch_bounds__(256) void k_front(const float* __restrict__ queries,
                                               const float* __restrict__ centroids,
                                               const int* __restrict__ db_list, int N,
                                               unsigned long long* __restrict__ keys_g,
                                               unsigned* __restrict__ counts) {
  const int t = threadIdx.x;
  const int r  = blockIdx.x % 3;
  const int b3 = blockIdx.x / 3;

  if (r == 0) {
    // ---- hist role (exact round-8 body, bid = b3, 256 roles) ----
    __shared__ unsigned hist_l[NLIST];
    for (int i = t; i < NLIST; i += 256) hist_l[i] = 0;
    __syncthreads();
    for (int n = b3 * 256 + t; n < N; n += 256 * 256)
      atomicAdd(&hist_l[db_list[n]], 1u);
    __syncthreads();
    for (int i = t; i < NLIST; i += 256)
      if (hist_l[i]) atomicAdd(&counts[i], hist_l[i]);
    return;
  }

  // ---- coarse role: cid in 0..511; query pair qg = cid>>2, part = cid&3 ----
  const int cid = b3 * 2 + (r - 1);
  const int qg = cid >> 2;
  const int part = cid & 3;
  const int qa = qg * 2, qb = qg * 2 + 1;
  __shared__ float qsa[DDIM], qsb[DDIM];
  if (t < DDIM) {
    qsa[t] = queries[qa * DDIM + t];
    qsb[t] = queries[qb * DDIM + t];
  }
  __syncthreads();
  const float qqa = xla_sumsq128(qsa);
  const float qqb = xla_sumsq128(qsb);
  const int c = part * 256 + t;
  const float* cr = centroids + (size_t)c * DDIM;
  float cbuf[DDIM];
  #pragma unroll
  for (int d = 0; d < DDIM; d += 4) {
    float4 cv = *(const float4*)(cr + d);
    cbuf[d] = cv.x; cbuf[d + 1] = cv.y; cbuf[d + 2] = cv.z; cbuf[d + 3] = cv.w;
  }
  const float cc = xla_sumsq128(cbuf);   // computed once, bit-exact for both queries
  float dota = 0.f, dotb = 0.f;
  #pragma unroll
  for (int d = 0; d < DDIM; ++d) {
    dota = __fmaf_rn(qsa[d], cbuf[d], dota);
    dotb = __fmaf_rn(qsb[d], cbuf[d], dotb);
  }
  float dista = __fsub_rn(__fadd_rn(qqa, cc), __fmul_rn(2.0f, dota));
  float distb = __fsub_rn(__fadd_rn(qqb, cc), __fmul_rn(2.0f, dotb));
  keys_g[(size_t)qa * NLIST + c] =
      ((unsigned long long)__float_as_uint(dista) << 32) | (unsigned)c;
  keys_g[(size_t)qb * NLIST + c] =
      ((unsigned long long)__float_as_uint(distb) << 32) | (unsigned)c;
}

// ------- prep: bucket scatter (nscat roles, SCHUNK=1024 — R12 showed 512
//         duplicates fixed per-block overhead) + per-query select/LUT (Q roles)
//         in one 512-thread dispatch (exact round-8 proven bodies).
__global__ __launch_bounds__(STHREADS) void k_prep(const float* __restrict__ queries,
                                                   const float* __restrict__ codebooks,
                                                   const unsigned long long* __restrict__ keys_g,
                                                   const int* __restrict__ db_list,
                                                   const int* __restrict__ db_codes, int N,
                                                   int Q,
                                                   const unsigned* __restrict__ counts,
                                                   unsigned* __restrict__ cursor,
                                                   int4* __restrict__ pack,
                                                   float* __restrict__ lut_g,
                                                   unsigned* __restrict__ probe_g) {
  const int t = threadIdx.x;
  const int bid = blockIdx.x;

  if (bid < Q) {
    // ---- select role: bst + LUT + coarse top-NPROBE -> probe descriptor ----
    const int qi = bid;
    __shared__ float qs[DDIM];
    __shared__ unsigned hist[HBINS];
    __shared__ unsigned long long coll[512];
    __shared__ unsigned bst[NLIST + 1];
    __shared__ unsigned pstart[NPROBE], pcum[NPROBE + 1];
    __shared__ unsigned wsum[16];
    __shared__ unsigned scnt;
    __shared__ int sT;

    if (t < DDIM) qs[t] = queries[qi * DDIM + t];
    for (int i = t; i < HBINS; i += STHREADS) hist[i] = 0;
    if (t == 0) { scnt = 0; sT = HBINS - 1; }
    const unsigned long long k0 = keys_g[(size_t)qi * NLIST + t];
    const unsigned long long k1 = keys_g[(size_t)qi * NLIST + t + STHREADS];
    {
      unsigned c0 = counts[2 * t], c1 = counts[2 * t + 1];
      unsigned s2 = c0 + c1;
      unsigned incl = block_scan_incl(s2, wsum, t, STHREADS / 64);
      bst[2 * t + 1] = incl - c1;
      bst[2 * t + 2] = incl;
      if (t == 0) bst[0] = 0;
    }
    __syncthreads();

    #pragma unroll
    for (int j = 0; j < (MSUB * KCODE) / STHREADS; ++j) {
      int idx = j * STHREADS + t;
      const float* cb = codebooks + (size_t)idx * DSUB;
      const float* qsub = qs + (idx >> 8) * DSUB;  // KCODE == 256
      float cbv[DSUB], qv[DSUB];
      #pragma unroll
      for (int d = 0; d < DSUB; d += 4) {
        float4 cv = *(const float4*)(cb + d);
        cbv[d] = cv.x; cbv[d + 1] = cv.y; cbv[d + 2] = cv.z; cbv[d + 3] = cv.w;
      }
      #pragma unroll
      for (int d = 0; d < DSUB; ++d) qv[d] = qsub[d];
      const float qq16 = xla_sumsq16(qv);
      const float cc16 = xla_sumsq16(cbv);
      const float dot16 = chain_dot16(qv, cbv);
      lut_g[(size_t)qi * (MSUB * KCODE) + idx] =
          __fsub_rn(__fadd_rn(qq16, cc16), __fmul_rn(2.0f, dot16));
    }

    atomicAdd(&hist[(unsigned)(k0 >> 51)], 1u);
    atomicAdd(&hist[(unsigned)(k1 >> 51)], 1u);
    __syncthreads();
    {
      unsigned mysum = 0;
      #pragma unroll
      for (int i = 0; i < HBINS / STHREADS; ++i) mysum += hist[t * (HBINS / STHREADS) + i];
      unsigned incl = block_scan_incl(mysum, wsum, t, STHREADS / 64);
      unsigned excl = incl - mysum;
      if (excl < NPROBE && NPROBE <= incl) {
        unsigned c2 = excl;
        #pragma unroll
        for (int i = 0; i < HBINS / STHREADS; ++i) {
          unsigned h = hist[t * (HBINS / STHREADS) + i];
          if (c2 + h >= NPROBE) { sT = t * (HBINS / STHREADS) + i; break; }
          c2 += h;
        }
      }
    }
    __syncthreads();
    {
      const int T32 = sT;
      if ((int)(k0 >> 51) <= T32) {
        unsigned p = atomicAdd(&scnt, 1u);
        if (p < 512) coll[p] = k0;
      }
      if ((int)(k1 >> 51) <= T32) {
        unsigned p = atomicAdd(&scnt, 1u);
        if (p < 512) coll[p] = k1;
      }
    }
    __syncthreads();
    {
      unsigned cnt = scnt; if (cnt > 512) cnt = 512;
      for (unsigned i = t; i < cnt; i += STHREADS) {
        unsigned long long k2 = coll[i];
        unsigned r = 0;
        for (unsigned j = 0; j < cnt; ++j) r += (coll[j] < k2) ? 1u : 0u;
        if (r < NPROBE) {
          unsigned l = (unsigned)(k2 & 0xffffffffULL);
          pstart[r] = bst[l];
          pcum[r + 1] = bst[l + 1] - bst[l];
        }
      }
    }
    __syncthreads();
    if (t == 0) {
      unsigned acc = 0;
      pcum[0] = 0;
      for (int j = 1; j <= NPROBE; ++j) { acc += pcum[j]; pcum[j] = acc; }
    }
    __syncthreads();
    if (t < NPROBE)     probe_g[qi * PSTRIDE + t] = pstart[t];
    if (t < NPROBE + 1) probe_g[qi * PSTRIDE + NPROBE + t] = pcum[t];
    return;
  }

  // ---- scatter role (exact round-8 body; chunk = bid - Q, SCHUNK = 1024) ----
  __shared__ unsigned lhist[NLIST], lbase[NLIST], sbstart[NLIST];
  __shared__ unsigned wsum2[16];
  const int base = (bid - Q) * SCHUNK;
  {
    unsigned c0 = counts[t * 2], c1 = counts[t * 2 + 1];
    unsigned sum2 = c0 + c1;
    unsigned incl = block_scan_incl(sum2, wsum2, t, STHREADS / 64);
    unsigned excl = incl - sum2;
    sbstart[t * 2] = excl;
    sbstart[t * 2 + 1] = excl + c0;
  }
  for (int i = t; i < NLIST; i += STHREADS) lhist[i] = 0;
  __syncthreads();
  #pragma unroll
  for (int k = 0; k < SCHUNK / STHREADS; ++k) {
    int n = base + k * STHREADS + t;
    if (n < N) atomicAdd(&lhist[db_list[n]], 1u);
  }
  __syncthreads();
  for (int i = t; i < NLIST; i += STHREADS) {
    unsigned cnt = lhist[i];
    if (cnt) lbase[i] = sbstart[i] + atomicAdd(&cursor[i], cnt);
    lhist[i] = 0;
  }
  __syncthreads();
  #pragma unroll
  for (int k = 0; k < SCHUNK / STHREADS; ++k) {
    int n = base + k * STHREADS + t;
    if (n < N) {
      int l = db_list[n];
      unsigned pos = lbase[l] + atomicAdd(&lhist[l], 1u);
      const int4* cp = (const int4*)(db_codes + (size_t)n * MSUB);
      int4 c0 = cp[0], c1 = cp[1];
      unsigned lo = (unsigned)(c0.x & 255) | ((unsigned)(c0.y & 255) << 8) |
                    ((unsigned)(c0.z & 255) << 16) | ((unsigned)(c0.w & 255) << 24);
      unsigned hi = (unsigned)(c1.x & 255) | ((unsigned)(c1.y & 255) << 8) |
                    ((unsigned)(c1.z & 255) << 16) | ((unsigned)(c1.w & 255) << 24);
      pack[pos] = make_int4((int)lo, (int)hi, n, 0);
    }
  }
}

// ---------------- search: ADC + top-k only (prologue precomputed in k_prep) ----
__global__ __launch_bounds__(1024, 1) void k_search(const float* __restrict__ lut_g,
                                                    const unsigned* __restrict__ probe_g,
                                                    const int4* __restrict__ pack,
                                                    int* __restrict__ out) {
  const int qi = blockIdx.x;
  const int t = threadIdx.x;
  __shared__ float lut_s[MSUB * KCODE];
  __shared__ unsigned hist[HBINS];
  __shared__ unsigned long long coll[COLL_CAP];
  __shared__ unsigned pstart[NPROBE], pcum[NPROBE + 1];
  __shared__ unsigned wsum[16];
  __shared__ unsigned scnt;
  __shared__ int sT;

  lut_s[t] = lut_g[(size_t)qi * (MSUB * KCODE) + t];
  lut_s[1024 + t] = lut_g[(size_t)qi * (MSUB * KCODE) + 1024 + t];
  for (int i = t; i < HBINS; i += 1024) hist[i] = 0;
  if (t < NPROBE)     pstart[t] = probe_g[qi * PSTRIDE + t];
  if (t < NPROBE + 1) pcum[t] = probe_g[qi * PSTRIDE + NPROBE + t];
  if (t == 0) { scnt = 0; sT = HBINS - 1; }
  __syncthreads();
  const unsigned total = pcum[NPROBE];

  // ---- pass 1: ADC once, keys in STATICALLY-indexed registers,
  //      probe lookup via monotonic walk (g strictly increases per thread) ----
  unsigned long long regkey[RCAP];
  int lo = 0;
  #pragma unroll
  for (int s = 0; s < RCAP; ++s) {
    unsigned g = (unsigned)t + (unsigned)(s * 1024);
    if (g < total) {
      while (pcum[lo + 1] <= g) ++lo;
      unsigned addr = pstart[lo] + (g - pcum[lo]);
      int4 w = pack[addr];
      unsigned long long code = (unsigned)w.x | ((unsigned long long)(unsigned)w.y << 32);
      unsigned bits = __float_as_uint(adc_dist(lut_s, code));
      regkey[s] = ((unsigned long long)bits << 32) | (unsigned)w.z;
      atomicAdd(&hist[bits >> 19], 1u);
    }
  }
  // defensive tail (never taken at this problem size: RCAP*1024 = 10240 > max total)
  for (unsigned g = (unsigned)t + RCAP * 1024; g < total; g += 1024) {
    while (pcum[lo + 1] <= g) ++lo;
    unsigned addr = pstart[lo] + (g - pcum[lo]);
    int4 w = pack[addr];
    unsigned long long code = (unsigned)w.x | ((unsigned long long)(unsigned)w.y << 32);
    unsigned bits = __float_as_uint(adc_dist(lut_s, code));
    atomicAdd(&hist[bits >> 19], 1u);
  }
  __syncthreads();

  // ---- find T = bin containing rank TOPK ----
  {
    unsigned mysum = 0;
    #pragma unroll
    for (int i = 0; i < 4; ++i) mysum += hist[t * 4 + i];
    unsigned incl = block_scan_incl(mysum, wsum, t, 16);
    unsigned excl = incl - mysum;
    if (excl < TOPK && TOPK <= incl) {
      unsigned c = excl;
      #pragma unroll
      for (int i = 0; i < 4; ++i) {
        unsigned h = hist[t * 4 + i];
        if (c + h >= TOPK) { sT = t * 4 + i; break; }
        c += h;
      }
    }
  }
  __syncthreads();
  const int T = sT;

  // ---- pass 2: collect ALL candidates with bin <= T (register replay) ----
  {
    #pragma unroll
    for (int s = 0; s < RCAP; ++s) {
      unsigned g = (unsigned)t + (unsigned)(s * 1024);
      if (g < total) {
        unsigned long long k2 = regkey[s];
        if ((int)(unsigned)(k2 >> 51) <= T) {   // == bits >> 19
          unsigned p = atomicAdd(&scnt, 1u);
          if (p < COLL_CAP) coll[p] = k2;
        }
      }
    }
    int lo2 = 0;
    for (unsigned g = (unsigned)t + RCAP * 1024; g < total; g += 1024) {
      while (pcum[lo2 + 1] <= g) ++lo2;
      unsigned addr = pstart[lo2] + (g - pcum[lo2]);
      int4 w = pack[addr];
      unsigned long long code = (unsigned)w.x | ((unsigned long long)(unsigned)w.y << 32);
      unsigned bits = __float_as_uint(adc_dist(lut_s, code));
      if ((int)(bits >> 19) <= T) {
        unsigned p = atomicAdd(&scnt, 1u);
        if (p < COLL_CAP) coll[p] = ((unsigned long long)bits << 32) | (unsigned)w.z;
      }
    }
  }
  __syncthreads();

  // ---- exact rank by (fp32 bits, index) ----
  unsigned cnt = scnt;
  if (cnt > COLL_CAP) cnt = COLL_CAP;
  for (unsigned i = t; i < cnt; i += 1024) {
    unsigned long long key = coll[i];
    unsigned r = 0;
    for (unsigned j = 0; j < cnt; ++j) r += (coll[j] < key) ? 1u : 0u;
    if (r < TOPK) out[qi * TOPK + r] = (int)(key & 0xffffffffULL);
  }
}

extern "C" void kernel_launch(void* const* d_in, const int* in_sizes, int n_in,
                              void* d_out, int out_size, void* d_ws, size_t ws_size,
                              hipStream_t stream) {
  const float* queries   = (const float*)d_in[0];
  const float* centroids = (const float*)d_in[1];
  const float* codebooks = (const float*)d_in[2];
  const int*   db_codes  = (const int*)d_in[3];
  const int*   db_list   = (const int*)d_in[4];
  const int N = in_sizes[4];
  const int Q = in_sizes[0] / DDIM;
  int* out = (int*)d_out;

  char* p = (char*)d_ws;
  unsigned long long* keys_g = (unsigned long long*)p; p += (size_t)Q * NLIST * 8;
  unsigned* counts = (unsigned*)p;                  p += NLIST * 4;
  unsigned* cursor = (unsigned*)p;                  p += NLIST * 4;
  int4* pack = (int4*)p;                            p += (size_t)N * 16;
  float* lut_g = (float*)p;                         p += (size_t)Q * MSUB * KCODE * 4;
  unsigned* probe_g = (unsigned*)p;                 p += (size_t)Q * PSTRIDE * 4;

  const int nscat = (N + SCHUNK - 1) / SCHUNK;

  hipMemsetAsync(counts, 0, (size_t)NLIST * 4 * 2, stream); // counts + cursor

  // 768 blocks: 256 hist roles + 512 two-query coarse roles (Q/2 * 4 parts)
  k_front<<<768, 256, 0, stream>>>(queries, centroids, db_list, N, keys_g, counts);
  k_prep<<<Q + nscat, STHREADS, 0, stream>>>(queries, codebooks, keys_g, db_list,
                                             db_codes, N, Q, counts, cursor, pack,
                                             lut_g, probe_g);
  k_search<<<Q, 1024, 0, stream>>>(lut_g, probe_g, pack, out);
}